// Round 4
// baseline (109.078 us; speedup 1.0000x reference)
//
#include <hip/hip_runtime.h>
#include <hip/hip_bf16.h>

// out[i] = sum_{j<512} r[batch[i,j]] + log(n_pos/n_neg)
// One 64-lane wave per row. Both 16B/lane nontemporal row loads issued up
// front (batch streamed once, no reuse -> keep it out of L2 which caches r),
// then 8 independent gathers from r (~201KB, L2-resident), butterfly reduce.

#define B_ROWS 16384
#define L_TOK  512
#define WAVES_PER_BLOCK 4   // 256 threads

typedef int v4i __attribute__((ext_vector_type(4)));

__global__ __launch_bounds__(256) void nb_score_kernel(
    const int* __restrict__ batch,       // [B, L] int32
    const float* __restrict__ r,         // [VOCAB] f32
    const int* __restrict__ n_pos,       // [1]
    const int* __restrict__ n_neg,       // [1]
    float* __restrict__ out)             // [B] f32
{
    const int lane = threadIdx.x & 63;
    const int wave = threadIdx.x >> 6;
    const int row  = blockIdx.x * WAVES_PER_BLOCK + wave;
    if (row >= B_ROWS) return;

    const v4i* bp = reinterpret_cast<const v4i*>(batch + (size_t)row * L_TOK);

    // Issue both token-vector loads first (2 x 16B per lane = 128B = row/64).
    v4i t0 = __builtin_nontemporal_load(&bp[lane]);
    v4i t1 = __builtin_nontemporal_load(&bp[64 + lane]);

    // 8 independent gathers -> 8 outstanding L2 requests per thread.
    float g0 = r[t0.x];
    float g1 = r[t0.y];
    float g2 = r[t0.z];
    float g3 = r[t0.w];
    float g4 = r[t1.x];
    float g5 = r[t1.y];
    float g6 = r[t1.z];
    float g7 = r[t1.w];

    float acc = ((g0 + g1) + (g2 + g3)) + ((g4 + g5) + (g6 + g7));

    // wave-64 butterfly reduce
#pragma unroll
    for (int off = 32; off > 0; off >>= 1)
        acc += __shfl_xor(acc, off, 64);

    if (lane == 0) {
        float log_prior = logf((float)n_pos[0] / (float)n_neg[0]);
        __builtin_nontemporal_store(acc + log_prior, &out[row]);
    }
}

extern "C" void kernel_launch(void* const* d_in, const int* in_sizes, int n_in,
                              void* d_out, int out_size, void* d_ws, size_t ws_size,
                              hipStream_t stream) {
    const int*   batch = (const int*)d_in[0];
    const float* r     = (const float*)d_in[1];
    const int*   n_pos = (const int*)d_in[2];
    const int*   n_neg = (const int*)d_in[3];
    float*       out   = (float*)d_out;

    dim3 grid(B_ROWS / WAVES_PER_BLOCK);  // 4096
    dim3 block(64 * WAVES_PER_BLOCK);     // 256
    nb_score_kernel<<<grid, block, 0, stream>>>(batch, r, n_pos, n_neg, out);
}

// Round 9
// 87.813 us; speedup vs baseline: 1.2422x; 1.2422x over previous
//
#include <hip/hip_runtime.h>
#include <hip/hip_bf16.h>

// out[i] = sum_{j<512} r[batch[i,j]] + log(n_pos/n_neg)
//
// Two-level gather: r[0:40960) staged in 160KB LDS (81.5% of uniform tokens
// served at LDS gather throughput, random indices ~2-4-way bank conflicts =
// near-free per m136); remaining 18.5% gather from L2 with sparse exec mask.
// batch streamed once with nontemporal 16B/lane loads. Fallback to the plain
// L2-gather kernel if the 160KB dynamic-LDS opt-in is rejected.

#define B_ROWS   16384
#define L_TOK    512
#define VOCAB    50257
#define C_ENTRIES 40960              // floats cached in LDS (160 KiB)
#define LDS_BYTES (C_ENTRIES * 4)

typedef int   v4i __attribute__((ext_vector_type(4)));
typedef float v4f __attribute__((ext_vector_type(4)));

// ---------------- LDS-staged kernel: 1024 thr (16 waves), 64 rows/block ----
#define BLK_T   1024
#define ROWS_PB 64                   // 16 waves x 4 rows
#define GRID_B  (B_ROWS / ROWS_PB)   // 256

static_assert(B_ROWS % ROWS_PB == 0, "grid divides rows");
static_assert((C_ENTRIES / 4) % BLK_T == 0, "staging loop exact");
static_assert(L_TOK == 64 * 4 * 2, "two v4i loads per lane per row");

__global__ __launch_bounds__(BLK_T, 1) void nb_lds_kernel(
    const int* __restrict__ batch, const float* __restrict__ r,
    const int* __restrict__ n_pos, const int* __restrict__ n_neg,
    float* __restrict__ out)
{
    extern __shared__ float rs[];

    // Stage r[0:C) coalesced as float4: 10240 vec4 / 1024 thr = 10 iters.
    {
        const v4f* r4 = reinterpret_cast<const v4f*>(r);
        v4f* rs4 = reinterpret_cast<v4f*>(rs);
#pragma unroll
        for (int i = 0; i < C_ENTRIES / 4 / BLK_T; ++i)
            rs4[i * BLK_T + threadIdx.x] = r4[i * BLK_T + threadIdx.x];
    }
    __syncthreads();

    const int lane = threadIdx.x & 63;
    const int wave = threadIdx.x >> 6;
    const int row0 = blockIdx.x * ROWS_PB + wave * 4;

    float log_prior = logf((float)n_pos[0] / (float)n_neg[0]);

#pragma unroll
    for (int k = 0; k < 4; ++k) {
        const int row = row0 + k;
        const v4i* bp = reinterpret_cast<const v4i*>(batch + (size_t)row * L_TOK);
        v4i t0 = __builtin_nontemporal_load(&bp[lane]);
        v4i t1 = __builtin_nontemporal_load(&bp[64 + lane]);

        int idx[8] = { t0.x, t0.y, t0.z, t0.w, t1.x, t1.y, t1.z, t1.w };
        float g[8];
#pragma unroll
        for (int e = 0; e < 8; ++e)
            g[e] = (idx[e] < C_ENTRIES) ? rs[idx[e]] : r[idx[e]];

        float acc = ((g[0] + g[1]) + (g[2] + g[3])) + ((g[4] + g[5]) + (g[6] + g[7]));
#pragma unroll
        for (int off = 32; off > 0; off >>= 1)
            acc += __shfl_xor(acc, off, 64);

        if (lane == 0)
            __builtin_nontemporal_store(acc + log_prior, &out[row]);
    }
}

// ---------------- fallback: plain L2-gather kernel (previous round) --------
#define WAVES_PER_BLOCK 4

__global__ __launch_bounds__(256) void nb_score_kernel(
    const int* __restrict__ batch, const float* __restrict__ r,
    const int* __restrict__ n_pos, const int* __restrict__ n_neg,
    float* __restrict__ out)
{
    const int lane = threadIdx.x & 63;
    const int wave = threadIdx.x >> 6;
    const int row  = blockIdx.x * WAVES_PER_BLOCK + wave;
    if (row >= B_ROWS) return;

    const v4i* bp = reinterpret_cast<const v4i*>(batch + (size_t)row * L_TOK);
    v4i t0 = __builtin_nontemporal_load(&bp[lane]);
    v4i t1 = __builtin_nontemporal_load(&bp[64 + lane]);

    float acc = ((r[t0.x] + r[t0.y]) + (r[t0.z] + r[t0.w]))
              + ((r[t1.x] + r[t1.y]) + (r[t1.z] + r[t1.w]));
#pragma unroll
    for (int off = 32; off > 0; off >>= 1)
        acc += __shfl_xor(acc, off, 64);

    if (lane == 0) {
        float log_prior = logf((float)n_pos[0] / (float)n_neg[0]);
        __builtin_nontemporal_store(acc + log_prior, &out[row]);
    }
}

extern "C" void kernel_launch(void* const* d_in, const int* in_sizes, int n_in,
                              void* d_out, int out_size, void* d_ws, size_t ws_size,
                              hipStream_t stream) {
    const int*   batch = (const int*)d_in[0];
    const float* r     = (const float*)d_in[1];
    const int*   n_pos = (const int*)d_in[2];
    const int*   n_neg = (const int*)d_in[3];
    float*       out   = (float*)d_out;

    // Opt in to 160KB dynamic LDS. Host-side attribute set, not a stream op:
    // graph-capture safe, deterministic result per process -> same branch
    // taken on every call.
    hipError_t e = hipFuncSetAttribute(
        reinterpret_cast<const void*>(nb_lds_kernel),
        hipFuncAttributeMaxDynamicSharedMemorySize, LDS_BYTES);

    if (e == hipSuccess) {
        nb_lds_kernel<<<GRID_B, BLK_T, LDS_BYTES, stream>>>(batch, r, n_pos, n_neg, out);
    } else {
        nb_score_kernel<<<B_ROWS / WAVES_PER_BLOCK, 64 * WAVES_PER_BLOCK, 0, stream>>>(
            batch, r, n_pos, n_neg, out);
    }
}